// Round 3
// baseline (16381.871 us; speedup 1.0000x reference)
//
#include <hip/hip_runtime.h>

// ESN forward, teacher-forced: s[t] = tanh(w@s[t-1] + w_in@in[t] + w_fb@out[t-1]) + 1e-3*(nu[t]-0.5)
// Persistent kernel, 256 blocks x 256 threads, one block per CU.
//   - block owns 8 rows; thread owns 8 rows x 8 cols of w in VGPRs (scalar "+v"
//     pins: no quad-alignment pressure; demand ~115 regs fits cleanly).
//   - state exchange via 8-byte {fp32, step-tag} words, agent scope, DOUBLE-
//     buffered AND 8x REPLICATED (one replica per XCD, consumer polls replica
//     blockIdx&7): round-2 counters showed 2.4us/step with only 8% VALUBusy and
//     a 40ms outlier => poll hot-line serialization; replicas cut per-line
//     readers 256 -> 32.
//   - one __syncthreads/step (red[] double-buffered by t&1); wave 0 does the
//     final sum + tanh + all 64 replica stores (lane = rep*8+row).

#define N_RES   2048
#define N_IN    64
#define N_OUT   32
#define T_STEPS 4096
#define NOISEC  0.001f
#define NBLK    256
#define NTHR    256
#define RPB     8     // rows per block
#define CPT     8     // state words (cols) per thread
#define NREP    8     // one replica per XCD

typedef float f32x4 __attribute__((ext_vector_type(4)));

#define PIN8F(a0,a1,a2,a3,a4,a5,a6,a7) \
    asm volatile("" : "+v"(a0),"+v"(a1),"+v"(a2),"+v"(a3), \
                      "+v"(a4),"+v"(a5),"+v"(a6),"+v"(a7))

__global__ void esn_init(unsigned long long* __restrict__ slots) {
    const int i = blockIdx.x * blockDim.x + threadIdx.x;
    if (i < NREP * 2 * N_RES)
        __hip_atomic_store(slots + i, 0ull, __ATOMIC_RELAXED, __HIP_MEMORY_SCOPE_AGENT);
}

__global__ __launch_bounds__(NTHR, 1)
void esn_run(const float* __restrict__ inputs,    // T x 64
             const float* __restrict__ outputs,   // T x 32
             const float* __restrict__ w,         // 2048 x 2048
             const float* __restrict__ w_in,      // 2048 x 64
             const float* __restrict__ w_feedb,   // 2048 x 32
             const float* __restrict__ out_w,     // 32 x 2048
             const float* __restrict__ out_b,     // 32
             const float* __restrict__ noise_u,   // T x 2048
             float* __restrict__ d_out,           // 32 + 2048
             unsigned long long* __restrict__ slots) { // NREP x 2 x 2048
    const int tid   = threadIdx.x;
    const int blk   = blockIdx.x;
    const int row0  = blk * RPB;
    const int wav   = tid >> 6;
    const int lan   = tid & 63;
    const int myrep = blk & (NREP - 1);

    __shared__ float red[2][4][RPB];

    // ---- persistent W fragment: 8 rows x my 8 contiguous columns, scalar regs ----
    float wvf[RPB * CPT];
    #pragma unroll
    for (int r = 0; r < RPB; ++r) {
        const float* wp = w + (size_t)(row0 + r) * N_RES + tid * CPT;
        const f32x4 u0 = *reinterpret_cast<const f32x4*>(wp);
        const f32x4 u1 = *reinterpret_cast<const f32x4*>(wp + 4);
        wvf[r*8+0]=u0.x; wvf[r*8+1]=u0.y; wvf[r*8+2]=u0.z; wvf[r*8+3]=u0.w;
        wvf[r*8+4]=u1.x; wvf[r*8+5]=u1.y; wvf[r*8+6]=u1.z; wvf[r*8+7]=u1.w;
    }
    float wex[RPB];
    #pragma unroll
    for (int r = 0; r < RPB; ++r) {
        float v = 0.f;
        if (tid < N_IN)              v = w_in[(row0 + r) * N_IN + tid];
        else if (tid < N_IN + N_OUT) v = w_feedb[(row0 + r) * N_OUT + (tid - N_IN)];
        wex[r] = v;
    }

    for (int t = 1; t < T_STEPS; ++t) {
        // liveness pins: scalar operands, no alignment constraints
        PIN8F(wvf[0],wvf[1],wvf[2],wvf[3],wvf[4],wvf[5],wvf[6],wvf[7]);
        PIN8F(wvf[8],wvf[9],wvf[10],wvf[11],wvf[12],wvf[13],wvf[14],wvf[15]);
        PIN8F(wvf[16],wvf[17],wvf[18],wvf[19],wvf[20],wvf[21],wvf[22],wvf[23]);
        PIN8F(wvf[24],wvf[25],wvf[26],wvf[27],wvf[28],wvf[29],wvf[30],wvf[31]);
        PIN8F(wvf[32],wvf[33],wvf[34],wvf[35],wvf[36],wvf[37],wvf[38],wvf[39]);
        PIN8F(wvf[40],wvf[41],wvf[42],wvf[43],wvf[44],wvf[45],wvf[46],wvf[47]);
        PIN8F(wvf[48],wvf[49],wvf[50],wvf[51],wvf[52],wvf[53],wvf[54],wvf[55]);
        PIN8F(wvf[56],wvf[57],wvf[58],wvf[59],wvf[60],wvf[61],wvf[62],wvf[63]);
        PIN8F(wex[0],wex[1],wex[2],wex[3],wex[4],wex[5],wex[6],wex[7]);

        // off-critical-path operands (issued before the poll, overlap with it)
        float xv = 0.f;
        if (tid < N_IN)              xv = inputs[t * N_IN + tid];
        else if (tid < N_IN + N_OUT) xv = outputs[(t - 1) * N_OUT + (tid - N_IN)];
        float nu = 0.f;
        if (wav == 0) nu = noise_u[(size_t)t * N_RES + row0 + (lan & 7)];

        // ---- poll my 8 tagged state words from MY XCD's replica ----
        const unsigned long long* sl =
            slots + ((size_t)(myrep * 2 + ((t - 1) & 1))) * N_RES + tid * CPT;
        const unsigned need = (unsigned)(t - 1);
        unsigned long long vv[CPT];
        #pragma unroll
        for (int i = 0; i < CPT; ++i)
            vv[i] = __hip_atomic_load(sl + i, __ATOMIC_RELAXED, __HIP_MEMORY_SCOPE_AGENT);
        for (;;) {
            unsigned mn = 0xffffffffu;
            #pragma unroll
            for (int i = 0; i < CPT; ++i) {
                const unsigned tg = (unsigned)(vv[i] >> 32);
                mn = (tg < mn) ? tg : mn;
            }
            if (mn >= need) break;
            #pragma unroll
            for (int i = 0; i < CPT; ++i)
                if ((unsigned)(vv[i] >> 32) < need)
                    vv[i] = __hip_atomic_load(sl + i, __ATOMIC_RELAXED, __HIP_MEMORY_SCOPE_AGENT);
        }

        // ---- partial dots: 8 rows x my 8 cols (64 FMA) ----
        float acc[RPB];
        #pragma unroll
        for (int r = 0; r < RPB; ++r) acc[r] = 0.f;
        #pragma unroll
        for (int i = 0; i < CPT; ++i) {
            const float sv = __uint_as_float((unsigned)(vv[i] & 0xffffffffu));
            #pragma unroll
            for (int r = 0; r < RPB; ++r)
                acc[r] = fmaf(wvf[r*8+i], sv, acc[r]);
        }
        #pragma unroll
        for (int r = 0; r < RPB; ++r) acc[r] = fmaf(wex[r], xv, acc[r]);

        // ---- wave reduce: halving exchange (1,2,4) then butterfly (8,16,32) ----
        {   const bool b = (lan & 1);
            #pragma unroll
            for (int r = 0; r < 4; ++r) {
                const float send = b ? acc[r] : acc[r + 4];
                const float got  = __shfl_xor(send, 1, 64);
                acc[r] = (b ? acc[r + 4] : acc[r]) + got;
            }
        }
        {   const bool b = (lan >> 1) & 1;
            #pragma unroll
            for (int r = 0; r < 2; ++r) {
                const float send = b ? acc[r] : acc[r + 2];
                const float got  = __shfl_xor(send, 2, 64);
                acc[r] = (b ? acc[r + 2] : acc[r]) + got;
            }
        }
        {   const bool b = (lan >> 2) & 1;
            const float send = b ? acc[0] : acc[1];
            const float got  = __shfl_xor(send, 4, 64);
            acc[0] = (b ? acc[1] : acc[0]) + got;
        }
        #pragma unroll
        for (int m = 8; m < 64; m <<= 1) acc[0] += __shfl_xor(acc[0], m, 64);
        if (lan < 8) {
            const int rb = 4 * (lan & 1) + 2 * ((lan >> 1) & 1) + ((lan >> 2) & 1);
            red[t & 1][wav][rb] = acc[0];
        }
        __syncthreads();

        // ---- wave 0: final sum + tanh + publish to ALL replicas ----
        if (wav == 0) {
            const int r = lan & 7;        // row within block
            const int x = lan >> 3;       // replica id
            const float tot = red[t & 1][0][r] + red[t & 1][1][r]
                            + red[t & 1][2][r] + red[t & 1][3][r];
            const float val = tanhf(tot) + NOISEC * (nu - 0.5f);
            const unsigned long long pk =
                ((unsigned long long)(unsigned)t << 32) |
                (unsigned long long)__float_as_uint(val);
            __hip_atomic_store(slots + ((size_t)(x * 2 + (t & 1))) * N_RES + row0 + r,
                               pk, __ATOMIC_RELAXED, __HIP_MEMORY_SCOPE_AGENT);
            if (t == T_STEPS - 1 && x == 0) d_out[32 + row0 + r] = val;
        }
        // no second barrier: red[] is double-buffered by t&1, and waves can't
        // reach the t+2 write of this buffer without passing t+1's barrier.
    }

    // ---- epilogue: block 0 computes readout = out_w @ s_final + out_b ----
    if (blk == 0) {
        const unsigned long long* sf =
            slots + ((size_t)(0 * 2 + ((T_STEPS - 1) & 1))) * N_RES;
        const int r2 = tid >> 3, j2 = tid & 7;     // 32 rows x 8 lanes
        const unsigned need = (unsigned)(T_STEPS - 1);
        float acc = 0.f;
        for (int c0 = 0; c0 < N_RES / 8; c0 += 8) { // 256 cols/lane, 8 at a time
            const unsigned long long* p = sf + j2 * (N_RES / 8) + c0;
            unsigned long long vv[8];
            #pragma unroll
            for (int i = 0; i < 8; ++i)
                vv[i] = __hip_atomic_load(p + i, __ATOMIC_RELAXED, __HIP_MEMORY_SCOPE_AGENT);
            for (;;) {
                unsigned mn = 0xffffffffu;
                #pragma unroll
                for (int i = 0; i < 8; ++i) {
                    const unsigned tg = (unsigned)(vv[i] >> 32);
                    mn = (tg < mn) ? tg : mn;
                }
                if (mn >= need) break;
                #pragma unroll
                for (int i = 0; i < 8; ++i)
                    if ((unsigned)(vv[i] >> 32) < need)
                        vv[i] = __hip_atomic_load(p + i, __ATOMIC_RELAXED, __HIP_MEMORY_SCOPE_AGENT);
            }
            #pragma unroll
            for (int i = 0; i < 8; ++i) {
                const float sv = __uint_as_float((unsigned)(vv[i] & 0xffffffffu));
                acc = fmaf(out_w[r2 * N_RES + j2 * (N_RES / 8) + c0 + i], sv, acc);
            }
        }
        #pragma unroll
        for (int m = 1; m < 8; m <<= 1) acc += __shfl_xor(acc, m, 64);
        if (j2 == 0) d_out[r2] = acc + out_b[r2];
    }
}

extern "C" void kernel_launch(void* const* d_in, const int* in_sizes, int n_in,
                              void* d_out, int out_size, void* d_ws, size_t ws_size,
                              hipStream_t stream) {
    const float* inputs  = (const float*)d_in[0];
    const float* outputs = (const float*)d_in[1];
    const float* w       = (const float*)d_in[2];
    const float* w_in    = (const float*)d_in[3];
    const float* w_feedb = (const float*)d_in[4];
    const float* out_w   = (const float*)d_in[5];
    const float* out_b   = (const float*)d_in[6];
    const float* noise_u = (const float*)d_in[7];
    unsigned long long* slots = (unsigned long long*)d_ws; // 8 reps x 2 x 2048 x 8B = 256 KB

    // re-init tags every call (d_ws is not re-poisoned between graph replays)
    esn_init<<<(NREP * 2 * N_RES + NTHR - 1) / NTHR, NTHR, 0, stream>>>(slots);
    esn_run<<<NBLK, NTHR, 0, stream>>>(inputs, outputs, w, w_in, w_feedb,
                                       out_w, out_b, noise_u,
                                       (float*)d_out, slots);
}

// Round 4
// 9351.765 us; speedup vs baseline: 1.7517x; 1.7517x over previous
//
#include <hip/hip_runtime.h>

// ESN forward, teacher-forced: s[t] = tanh(w@s[t-1] + w_in@in[t] + w_fb@out[t-1]) + 1e-3*(nu[t]-0.5)
// Persistent kernel, 256 blocks x 256 threads, one block per CU, 8 rows/block.
//
// Design after rounds 1-3:
//   - W is NOT register-resident (LLVM remats loads past any "+v" pin; proven
//     twice: VGPR_Count=92/56 << demand). W streams from per-XCD L2 every step
//     (2 MB slice/XCD, L2-resident) -- off the coherence fabric, ~200ns/step.
//   - STRIDED column ownership: thread tid owns cols {tid, 256+tid, ..., 1792+tid}.
//     Poll loads are lane-consecutive (8 lines/wave-instr, not 64): 8x fewer
//     agent-scope requests at the L3 coherence point per sweep. W loads stay
//     perfectly coalesced (consecutive lanes, consecutive dwords).
//   - NO replication (round 3: 8x WRITE_SIZE, +70% dur). One {fp32,tag} word
//     per state element, double-buffered by step parity. Tag fused with data:
//     single 8B atomic load/store, no fences. Accepted tag in buf[(t-1)&1] can
//     only be t-1 (t+1 needs this block's own step-t publish -- impossible).
//   - s_sleep(1) pacing in poll retry: tames request-storm congestion + the
//     40-57ms outlier dispatches seen in rounds 2/3.
//   - one __syncthreads/step (red[] double-buffered by t&1); wave 0 finalizes:
//     4-partial sum + tanh + noise + single 64B-line publish (lanes 0-7).

#define N_RES   2048
#define N_IN    64
#define N_OUT   32
#define T_STEPS 4096
#define NOISEC  0.001f
#define NBLK    256
#define NTHR    256
#define RPB     8     // rows per block
#define CPT     8     // state words (cols) per thread, stride NTHR

__global__ void esn_init(unsigned long long* __restrict__ slots) {
    const int i = blockIdx.x * blockDim.x + threadIdx.x;
    if (i < 2 * N_RES)
        __hip_atomic_store(slots + i, 0ull, __ATOMIC_RELAXED, __HIP_MEMORY_SCOPE_AGENT);
}

__global__ __launch_bounds__(NTHR, 1)
void esn_run(const float* __restrict__ inputs,    // T x 64
             const float* __restrict__ outputs,   // T x 32
             const float* __restrict__ w,         // 2048 x 2048
             const float* __restrict__ w_in,      // 2048 x 64
             const float* __restrict__ w_feedb,   // 2048 x 32
             const float* __restrict__ out_w,     // 32 x 2048
             const float* __restrict__ out_b,     // 32
             const float* __restrict__ noise_u,   // T x 2048
             float* __restrict__ d_out,           // 32 + 2048
             unsigned long long* __restrict__ slots) { // 2 x 2048 tagged words
    const int tid  = threadIdx.x;
    const int blk  = blockIdx.x;
    const int row0 = blk * RPB;
    const int wav  = tid >> 6;
    const int lan  = tid & 63;

    __shared__ float red[2][4][RPB];

    // w_in / w_feedb: one virtual column per thread (tid<96)
    float wex[RPB];
    #pragma unroll
    for (int r = 0; r < RPB; ++r) {
        float v = 0.f;
        if (tid < N_IN)              v = w_in[(row0 + r) * N_IN + tid];
        else if (tid < N_IN + N_OUT) v = w_feedb[(row0 + r) * N_OUT + (tid - N_IN)];
        wex[r] = v;
    }

    const float* wp = w + (size_t)row0 * N_RES + tid;   // + r*N_RES + i*NTHR

    for (int t = 1; t < T_STEPS; ++t) {
        // off-critical-path operands (issued before the poll, overlap with it)
        float xv = 0.f;
        if (tid < N_IN)              xv = inputs[t * N_IN + tid];
        else if (tid < N_IN + N_OUT) xv = outputs[(t - 1) * N_OUT + (tid - N_IN)];
        float nu = 0.f;
        if (tid < RPB) nu = noise_u[(size_t)t * N_RES + row0 + tid];

        // ---- poll my 8 strided state words (lane-coalesced, agent scope) ----
        const unsigned long long* sl = slots + (size_t)((t - 1) & 1) * N_RES + tid;
        const unsigned need = (unsigned)(t - 1);
        unsigned long long vv[CPT];
        #pragma unroll
        for (int i = 0; i < CPT; ++i)
            vv[i] = __hip_atomic_load(sl + i * NTHR, __ATOMIC_RELAXED, __HIP_MEMORY_SCOPE_AGENT);
        for (;;) {
            unsigned mn = 0xffffffffu;
            #pragma unroll
            for (int i = 0; i < CPT; ++i) {
                const unsigned tg = (unsigned)(vv[i] >> 32);
                mn = (tg < mn) ? tg : mn;
            }
            if (mn >= need) break;
            __builtin_amdgcn_s_sleep(1);   // pace the retry storm
            #pragma unroll
            for (int i = 0; i < CPT; ++i)
                if ((unsigned)(vv[i] >> 32) < need)
                    vv[i] = __hip_atomic_load(sl + i * NTHR, __ATOMIC_RELAXED, __HIP_MEMORY_SCOPE_AGENT);
        }

        // ---- partial dots: 8 rows x my 8 strided cols, W streamed from L2 ----
        float acc[RPB];
        #pragma unroll
        for (int r = 0; r < RPB; ++r) acc[r] = 0.f;
        #pragma unroll
        for (int i = 0; i < CPT; ++i) {
            const float sv = __uint_as_float((unsigned)(vv[i] & 0xffffffffu));
            #pragma unroll
            for (int r = 0; r < RPB; ++r)
                acc[r] = fmaf(wp[(size_t)r * N_RES + i * NTHR], sv, acc[r]);
        }
        #pragma unroll
        for (int r = 0; r < RPB; ++r) acc[r] = fmaf(wex[r], xv, acc[r]);

        // ---- wave reduce: halving exchange (1,2,4) then butterfly (8,16,32) ----
        {   const bool b = (lan & 1);
            #pragma unroll
            for (int r = 0; r < 4; ++r) {
                const float send = b ? acc[r] : acc[r + 4];
                const float got  = __shfl_xor(send, 1, 64);
                acc[r] = (b ? acc[r + 4] : acc[r]) + got;
            }
        }
        {   const bool b = (lan >> 1) & 1;
            #pragma unroll
            for (int r = 0; r < 2; ++r) {
                const float send = b ? acc[r] : acc[r + 2];
                const float got  = __shfl_xor(send, 2, 64);
                acc[r] = (b ? acc[r + 2] : acc[r]) + got;
            }
        }
        {   const bool b = (lan >> 2) & 1;
            const float send = b ? acc[0] : acc[1];
            const float got  = __shfl_xor(send, 4, 64);
            acc[0] = (b ? acc[1] : acc[0]) + got;
        }
        #pragma unroll
        for (int m = 8; m < 64; m <<= 1) acc[0] += __shfl_xor(acc[0], m, 64);
        if (lan < 8) {
            const int rb = 4 * (lan & 1) + 2 * ((lan >> 1) & 1) + ((lan >> 2) & 1);
            red[t & 1][wav][rb] = acc[0];
        }
        __syncthreads();

        // ---- wave 0, lanes 0-7: final sum + tanh + single-line publish ----
        if (tid < RPB) {
            const float tot = red[t & 1][0][tid] + red[t & 1][1][tid]
                            + red[t & 1][2][tid] + red[t & 1][3][tid];
            const float val = tanhf(tot) + NOISEC * (nu - 0.5f);
            const unsigned long long pk =
                ((unsigned long long)(unsigned)t << 32) |
                (unsigned long long)__float_as_uint(val);
            __hip_atomic_store(slots + (size_t)(t & 1) * N_RES + row0 + tid, pk,
                               __ATOMIC_RELAXED, __HIP_MEMORY_SCOPE_AGENT);
            if (t == T_STEPS - 1) d_out[32 + row0 + tid] = val;
        }
        // no second barrier: red[] double-buffered by t&1; any wave's next
        // write to this buffer is behind the t+1 barrier, after wave0's read.
    }

    // ---- epilogue: block 0 computes readout = out_w @ s_final + out_b ----
    if (blk == 0) {
        const unsigned long long* sf = slots + (size_t)((T_STEPS - 1) & 1) * N_RES;
        const int r2 = tid >> 3, j2 = tid & 7;     // 32 rows x 8 lanes
        const unsigned need = (unsigned)(T_STEPS - 1);
        float acc = 0.f;
        for (int c0 = 0; c0 < N_RES / 8; c0 += 8) { // 256 cols/lane, 8 at a time
            const unsigned long long* p = sf + j2 * (N_RES / 8) + c0;
            unsigned long long vv[8];
            #pragma unroll
            for (int i = 0; i < 8; ++i)
                vv[i] = __hip_atomic_load(p + i, __ATOMIC_RELAXED, __HIP_MEMORY_SCOPE_AGENT);
            for (;;) {
                unsigned mn = 0xffffffffu;
                #pragma unroll
                for (int i = 0; i < 8; ++i) {
                    const unsigned tg = (unsigned)(vv[i] >> 32);
                    mn = (tg < mn) ? tg : mn;
                }
                if (mn >= need) break;
                __builtin_amdgcn_s_sleep(1);
                #pragma unroll
                for (int i = 0; i < 8; ++i)
                    if ((unsigned)(vv[i] >> 32) < need)
                        vv[i] = __hip_atomic_load(p + i, __ATOMIC_RELAXED, __HIP_MEMORY_SCOPE_AGENT);
            }
            #pragma unroll
            for (int i = 0; i < 8; ++i) {
                const float sv = __uint_as_float((unsigned)(vv[i] & 0xffffffffu));
                acc = fmaf(out_w[r2 * N_RES + j2 * (N_RES / 8) + c0 + i], sv, acc);
            }
        }
        #pragma unroll
        for (int m = 1; m < 8; m <<= 1) acc += __shfl_xor(acc, m, 64);
        if (j2 == 0) d_out[r2] = acc + out_b[r2];
    }
}

extern "C" void kernel_launch(void* const* d_in, const int* in_sizes, int n_in,
                              void* d_out, int out_size, void* d_ws, size_t ws_size,
                              hipStream_t stream) {
    const float* inputs  = (const float*)d_in[0];
    const float* outputs = (const float*)d_in[1];
    const float* w       = (const float*)d_in[2];
    const float* w_in    = (const float*)d_in[3];
    const float* w_feedb = (const float*)d_in[4];
    const float* out_w   = (const float*)d_in[5];
    const float* out_b   = (const float*)d_in[6];
    const float* noise_u = (const float*)d_in[7];
    unsigned long long* slots = (unsigned long long*)d_ws; // 2 x 2048 x 8B = 32 KB

    // re-init tags every call (d_ws is not re-poisoned between graph replays)
    esn_init<<<(2 * N_RES + NTHR - 1) / NTHR, NTHR, 0, stream>>>(slots);
    esn_run<<<NBLK, NTHR, 0, stream>>>(inputs, outputs, w, w_in, w_feedb,
                                       out_w, out_b, noise_u,
                                       (float*)d_out, slots);
}

// Round 5
// 8087.292 us; speedup vs baseline: 2.0256x; 1.1564x over previous
//
#include <hip/hip_runtime.h>

// ESN forward, teacher-forced: s[t] = tanh(w@s[t-1] + w_in@in[t] + w_fb@out[t-1]) + 1e-3*(nu[t]-0.5)
// Persistent kernel, 256 blocks x 256 threads, one block per CU, 8 rows/block.
//
// Round-4 postmortem: strided polls killed the outliers but only -5% dur =>
// fabric congestion is NOT the bottleneck; the serial chain is. The one
// state-INDEPENDENT piece still on the critical path was the 64KB/step W read
// issued after detect. This round:
//   - W lives in LDS (loaded once). Per step, all 16 ds_read_b128 are issued
//     BEFORE the poll loop, fenced by asm("":::"memory") so they cannot sink.
//     ds_read -> lgkmcnt, poll atomics -> vmcnt: independent counters, the
//     prefetch rides out the wait for free. FMA pays only residual lgkmcnt.
//   - LDS layout [r/4][cc][tid][r%4]: thread reads 16B contiguous, lane stride
//     16B => 2-way bank aliasing (free per m136). 16B-aligned for b128.
//   - fast tanh on the publish tail: 1 - 2*rcp(exp2(2.885*x)+1), ~5 VALU ops,
//     exact +-1 saturation at overflow, ~1e-7 abs error << 3e-2 threshold.
//   - state exchange unchanged (round 4): {fp32,tag} words, agent scope,
//     double-buffered, strided ownership, s_sleep(1) pacing.

#define N_RES   2048
#define N_IN    64
#define N_OUT   32
#define T_STEPS 4096
#define NOISEC  0.001f
#define NBLK    256
#define NTHR    256
#define RPB     8     // rows per block
#define CPT     8     // state words (cols) per thread, stride NTHR

typedef float f32x4 __attribute__((ext_vector_type(4)));

__device__ __forceinline__ float fast_tanh(float x) {
    // tanh(x) = 1 - 2/(e^{2x}+1);  e^{2x} = exp2(2*log2(e)*x)
    const float e = __builtin_amdgcn_exp2f(2.8853900818f * x);
    return fmaf(-2.f, __builtin_amdgcn_rcpf(e + 1.f), 1.f);
}

__global__ void esn_init(unsigned long long* __restrict__ slots) {
    const int i = blockIdx.x * blockDim.x + threadIdx.x;
    if (i < 2 * N_RES)
        __hip_atomic_store(slots + i, 0ull, __ATOMIC_RELAXED, __HIP_MEMORY_SCOPE_AGENT);
}

__global__ __launch_bounds__(NTHR, 1)
void esn_run(const float* __restrict__ inputs,    // T x 64
             const float* __restrict__ outputs,   // T x 32
             const float* __restrict__ w,         // 2048 x 2048
             const float* __restrict__ w_in,      // 2048 x 64
             const float* __restrict__ w_feedb,   // 2048 x 32
             const float* __restrict__ out_w,     // 32 x 2048
             const float* __restrict__ out_b,     // 32
             const float* __restrict__ noise_u,   // T x 2048
             float* __restrict__ d_out,           // 32 + 2048
             unsigned long long* __restrict__ slots) { // 2 x 2048 tagged words
    const int tid  = threadIdx.x;
    const int blk  = blockIdx.x;
    const int row0 = blk * RPB;
    const int wav  = tid >> 6;
    const int lan  = tid & 63;

    // [rr][cc][tid][j]: element (row = rr*4+j, col = cc*256+tid). 64KB.
    __shared__ float wlds[2 * 8 * NTHR * 4];
    __shared__ float red[2][4][RPB];

    // ---- one-time: stage my block's 8 W rows into LDS (coalesced reads) ----
    #pragma unroll
    for (int r = 0; r < RPB; ++r)
        #pragma unroll
        for (int cc = 0; cc < 8; ++cc) {
            const float v = w[(size_t)(row0 + r) * N_RES + cc * NTHR + tid];
            wlds[(((r >> 2) * 8 + cc) * NTHR + tid) * 4 + (r & 3)] = v;
        }
    // w_in / w_feedb: one virtual column per thread (tid<96)
    float wex[RPB];
    #pragma unroll
    for (int r = 0; r < RPB; ++r) {
        float v = 0.f;
        if (tid < N_IN)              v = w_in[(row0 + r) * N_IN + tid];
        else if (tid < N_IN + N_OUT) v = w_feedb[(row0 + r) * N_OUT + (tid - N_IN)];
        wex[r] = v;
    }
    __syncthreads();

    for (int t = 1; t < T_STEPS; ++t) {
        // ---- prefetch W fragment from LDS (state-independent), pre-poll ----
        f32x4 wv[16];
        #pragma unroll
        for (int rr = 0; rr < 2; ++rr)
            #pragma unroll
            for (int cc = 0; cc < 8; ++cc)
                wv[rr * 8 + cc] = *reinterpret_cast<const f32x4*>(
                    &wlds[((rr * 8 + cc) * NTHR + tid) * 4]);

        // off-critical-path operands (issued before the poll, overlap with it)
        float xv = 0.f;
        if (tid < N_IN)              xv = inputs[t * N_IN + tid];
        else if (tid < N_IN + N_OUT) xv = outputs[(t - 1) * N_OUT + (tid - N_IN)];
        float nu = 0.f;
        if (tid < RPB) nu = noise_u[(size_t)t * N_RES + row0 + tid];

        // fence: ds_reads above may not sink below (lgkmcnt is independent of
        // the poll's vmcnt, so the prefetch overlaps the wait)
        asm volatile("" ::: "memory");

        // ---- poll my 8 strided state words (lane-coalesced, agent scope) ----
        const unsigned long long* sl = slots + (size_t)((t - 1) & 1) * N_RES + tid;
        const unsigned need = (unsigned)(t - 1);
        unsigned long long vv[CPT];
        #pragma unroll
        for (int i = 0; i < CPT; ++i)
            vv[i] = __hip_atomic_load(sl + i * NTHR, __ATOMIC_RELAXED, __HIP_MEMORY_SCOPE_AGENT);
        for (;;) {
            unsigned mn = 0xffffffffu;
            #pragma unroll
            for (int i = 0; i < CPT; ++i) {
                const unsigned tg = (unsigned)(vv[i] >> 32);
                mn = (tg < mn) ? tg : mn;
            }
            if (mn >= need) break;
            __builtin_amdgcn_s_sleep(1);   // pace the retry
            #pragma unroll
            for (int i = 0; i < CPT; ++i)
                if ((unsigned)(vv[i] >> 32) < need)
                    vv[i] = __hip_atomic_load(sl + i * NTHR, __ATOMIC_RELAXED, __HIP_MEMORY_SCOPE_AGENT);
        }

        // ---- partial dots: 8 rows x my 8 strided cols, W from registers ----
        float acc[RPB];
        #pragma unroll
        for (int r = 0; r < RPB; ++r) acc[r] = 0.f;
        #pragma unroll
        for (int i = 0; i < CPT; ++i) {
            const float sv = __uint_as_float((unsigned)(vv[i] & 0xffffffffu));
            #pragma unroll
            for (int rr = 0; rr < 2; ++rr)
                #pragma unroll
                for (int j = 0; j < 4; ++j)
                    acc[rr * 4 + j] = fmaf(wv[rr * 8 + i][j], sv, acc[rr * 4 + j]);
        }
        #pragma unroll
        for (int r = 0; r < RPB; ++r) acc[r] = fmaf(wex[r], xv, acc[r]);

        // ---- wave reduce: halving exchange (1,2,4) then butterfly (8,16,32) ----
        {   const bool b = (lan & 1);
            #pragma unroll
            for (int r = 0; r < 4; ++r) {
                const float send = b ? acc[r] : acc[r + 4];
                const float got  = __shfl_xor(send, 1, 64);
                acc[r] = (b ? acc[r + 4] : acc[r]) + got;
            }
        }
        {   const bool b = (lan >> 1) & 1;
            #pragma unroll
            for (int r = 0; r < 2; ++r) {
                const float send = b ? acc[r] : acc[r + 2];
                const float got  = __shfl_xor(send, 2, 64);
                acc[r] = (b ? acc[r + 2] : acc[r]) + got;
            }
        }
        {   const bool b = (lan >> 2) & 1;
            const float send = b ? acc[0] : acc[1];
            const float got  = __shfl_xor(send, 4, 64);
            acc[0] = (b ? acc[1] : acc[0]) + got;
        }
        #pragma unroll
        for (int m = 8; m < 64; m <<= 1) acc[0] += __shfl_xor(acc[0], m, 64);
        if (lan < 8) {
            const int rb = 4 * (lan & 1) + 2 * ((lan >> 1) & 1) + ((lan >> 2) & 1);
            red[t & 1][wav][rb] = acc[0];
        }
        __syncthreads();

        // ---- wave 0, lanes 0-7: final sum + tanh + single-line publish ----
        if (tid < RPB) {
            const float tot = red[t & 1][0][tid] + red[t & 1][1][tid]
                            + red[t & 1][2][tid] + red[t & 1][3][tid];
            const float val = fast_tanh(tot) + NOISEC * (nu - 0.5f);
            const unsigned long long pk =
                ((unsigned long long)(unsigned)t << 32) |
                (unsigned long long)__float_as_uint(val);
            __hip_atomic_store(slots + (size_t)(t & 1) * N_RES + row0 + tid, pk,
                               __ATOMIC_RELAXED, __HIP_MEMORY_SCOPE_AGENT);
            if (t == T_STEPS - 1) d_out[32 + row0 + tid] = val;
        }
        // no second barrier: red[] double-buffered by t&1; any wave's next
        // write to this buffer is behind the t+1 barrier, after wave0's read.
    }

    // ---- epilogue: block 0 computes readout = out_w @ s_final + out_b ----
    if (blk == 0) {
        const unsigned long long* sf = slots + (size_t)((T_STEPS - 1) & 1) * N_RES;
        const int r2 = tid >> 3, j2 = tid & 7;     // 32 rows x 8 lanes
        const unsigned need = (unsigned)(T_STEPS - 1);
        float acc = 0.f;
        for (int c0 = 0; c0 < N_RES / 8; c0 += 8) { // 256 cols/lane, 8 at a time
            const unsigned long long* p = sf + j2 * (N_RES / 8) + c0;
            unsigned long long vv[8];
            #pragma unroll
            for (int i = 0; i < 8; ++i)
                vv[i] = __hip_atomic_load(p + i, __ATOMIC_RELAXED, __HIP_MEMORY_SCOPE_AGENT);
            for (;;) {
                unsigned mn = 0xffffffffu;
                #pragma unroll
                for (int i = 0; i < 8; ++i) {
                    const unsigned tg = (unsigned)(vv[i] >> 32);
                    mn = (tg < mn) ? tg : mn;
                }
                if (mn >= need) break;
                __builtin_amdgcn_s_sleep(1);
                #pragma unroll
                for (int i = 0; i < 8; ++i)
                    if ((unsigned)(vv[i] >> 32) < need)
                        vv[i] = __hip_atomic_load(p + i, __ATOMIC_RELAXED, __HIP_MEMORY_SCOPE_AGENT);
            }
            #pragma unroll
            for (int i = 0; i < 8; ++i) {
                const float sv = __uint_as_float((unsigned)(vv[i] & 0xffffffffu));
                acc = fmaf(out_w[r2 * N_RES + j2 * (N_RES / 8) + c0 + i], sv, acc);
            }
        }
        #pragma unroll
        for (int m = 1; m < 8; m <<= 1) acc += __shfl_xor(acc, m, 64);
        if (j2 == 0) d_out[r2] = acc + out_b[r2];
    }
}

extern "C" void kernel_launch(void* const* d_in, const int* in_sizes, int n_in,
                              void* d_out, int out_size, void* d_ws, size_t ws_size,
                              hipStream_t stream) {
    const float* inputs  = (const float*)d_in[0];
    const float* outputs = (const float*)d_in[1];
    const float* w       = (const float*)d_in[2];
    const float* w_in    = (const float*)d_in[3];
    const float* w_feedb = (const float*)d_in[4];
    const float* out_w   = (const float*)d_in[5];
    const float* out_b   = (const float*)d_in[6];
    const float* noise_u = (const float*)d_in[7];
    unsigned long long* slots = (unsigned long long*)d_ws; // 2 x 2048 x 8B = 32 KB

    // re-init tags every call (d_ws is not re-poisoned between graph replays)
    esn_init<<<(2 * N_RES + NTHR - 1) / NTHR, NTHR, 0, stream>>>(slots);
    esn_run<<<NBLK, NTHR, 0, stream>>>(inputs, outputs, w, w_in, w_feedb,
                                       out_w, out_b, noise_u,
                                       (float*)d_out, slots);
}